// Round 1
// baseline (452.495 us; speedup 1.0000x reference)
//
#include <hip/hip_runtime.h>

#define IN_C 64
#define OUT_C 16
#define EA_D 8

// ---------------- h = x @ lin_w + lin_b ----------------
// block = 256 threads = 16 nodes x 16 channels
__global__ __launch_bounds__(256) void h_kernel(
    const float* __restrict__ x,
    const float* __restrict__ lin_w,   // [64,16]
    const float* __restrict__ lin_b,   // [16]
    float* __restrict__ h,             // [N,16]
    int n)
{
    __shared__ float s_w[IN_C * OUT_C];      // 1024
    __shared__ float s_b[OUT_C];
    __shared__ float s_x[16][IN_C + 1];      // +1 pad: kill 4-way bank conflict

    const int t = threadIdx.x;
    for (int i = t; i < IN_C * OUT_C; i += 256) s_w[i] = lin_w[i];
    if (t < OUT_C) s_b[t] = lin_b[t];

    const int nodeBase = blockIdx.x * 16;
    // cooperative coalesced load of 16 x-rows (1024 floats, 4/thread)
    for (int i = t; i < 16 * IN_C; i += 256) {
        const int lr = i / IN_C, k = i % IN_C;
        const int node = nodeBase + lr;
        s_x[lr][k] = (node < n) ? x[node * IN_C + k] : 0.0f;
    }
    __syncthreads();

    const int lr = t >> 4;          // local node 0..15
    const int c  = t & 15;          // channel 0..15
    const int node = nodeBase + lr;
    if (node < n) {
        float acc = s_b[c];
        #pragma unroll
        for (int k = 0; k < IN_C; ++k)
            acc = fmaf(s_x[lr][k], s_w[k * OUT_C + c], acc);
        h[node * OUT_C + c] = acc;
    }
}

// ---------------- per-edge fused kernel ----------------
// one thread per edge; 16 channels in registers
__global__ __launch_bounds__(256) void edge_kernel(
    const int*   __restrict__ edge_index,  // [2,E]
    const float* __restrict__ edge_attr,   // [E,8]
    const float* __restrict__ ea_w,        // [8,16]
    const float* __restrict__ ea_b,        // [16]
    const float* __restrict__ w1,          // [16]
    const float* __restrict__ b1,          // [16]
    const float* __restrict__ w2,          // [16]
    const float* __restrict__ b2,          // [1]
    const float* __restrict__ h,           // [N,16]
    float*       __restrict__ out,         // [N,16]
    int E)
{
    __shared__ float s_eaw[EA_D * OUT_C];  // 128
    __shared__ float s_eab[OUT_C];
    __shared__ float s_w1[OUT_C], s_b1[OUT_C], s_w2[OUT_C];
    __shared__ float s_b2;

    const int t = threadIdx.x;
    if (t < EA_D * OUT_C)            s_eaw[t]       = ea_w[t];
    else if (t < 128 + OUT_C)        s_eab[t - 128] = ea_b[t - 128];
    else if (t < 144 + OUT_C)        s_w1[t - 144]  = w1[t - 144];
    else if (t < 160 + OUT_C)        s_b1[t - 160]  = b1[t - 160];
    else if (t < 176 + OUT_C)        s_w2[t - 176]  = w2[t - 176];
    else if (t == 192)               s_b2           = b2[0];
    __syncthreads();

    const int e = blockIdx.x * 256 + t;
    if (e >= E) return;

    const int row = edge_index[e] - 1;     // edge_index[0][e] - 1
    const int col = edge_index[E + e];     // edge_index[1][e]

    // edge_attr row: 8 floats, two float4 loads
    const float4* ap = (const float4*)(edge_attr + (size_t)e * EA_D);
    float4 a0 = ap[0], a1 = ap[1];
    float attr[EA_D] = {a0.x, a0.y, a0.z, a0.w, a1.x, a1.y, a1.z, a1.w};

    // gather h[col] : 16 floats, four float4 loads
    const float4* hp = (const float4*)(h + (size_t)col * OUT_C);
    float4 h0 = hp[0], h1 = hp[1], h2 = hp[2], h3 = hp[3];
    float hv[OUT_C] = {h0.x, h0.y, h0.z, h0.w, h1.x, h1.y, h1.z, h1.w,
                       h2.x, h2.y, h2.z, h2.w, h3.x, h3.y, h3.z, h3.w};

    // agg[c] = h[col][c] * (edge_attr @ ea_w + ea_b)[c]
    float agg[OUT_C];
    #pragma unroll
    for (int c = 0; c < OUT_C; ++c) {
        float acc = s_eab[c];
        #pragma unroll
        for (int k = 0; k < EA_D; ++k)
            acc = fmaf(attr[k], s_eaw[k * OUT_C + c], acc);
        agg[c] = hv[c] * acc;
    }

    // scores[c] = b2 + sum_j relu(agg[c]*w1[j]+b1[j]) * w2[j]
    float sc[OUT_C];
    float mx = -1e30f;
    #pragma unroll
    for (int c = 0; c < OUT_C; ++c) {
        float s = s_b2;
        #pragma unroll
        for (int j = 0; j < OUT_C; ++j) {
            float hmid = fmaf(agg[c], s_w1[j], s_b1[j]);
            hmid = fmaxf(hmid, 0.0f);
            s = fmaf(hmid, s_w2[j], s);
        }
        sc[c] = s;
        mx = fmaxf(mx, s);
    }

    // softmax over the 16 channels (in registers)
    float denom = 0.0f;
    #pragma unroll
    for (int c = 0; c < OUT_C; ++c) {
        sc[c] = __expf(sc[c] - mx);
        denom += sc[c];
    }
    const float inv = 1.0f / denom;

    // scatter-add
    float* orow = out + (size_t)row * OUT_C;
    #pragma unroll
    for (int c = 0; c < OUT_C; ++c)
        atomicAdd(orow + c, agg[c] * sc[c] * inv);
}

extern "C" void kernel_launch(void* const* d_in, const int* in_sizes, int n_in,
                              void* d_out, int out_size, void* d_ws, size_t ws_size,
                              hipStream_t stream)
{
    const float* x          = (const float*)d_in[0];
    const int*   edge_index = (const int*)  d_in[1];
    const float* edge_attr  = (const float*)d_in[2];
    const float* lin_w      = (const float*)d_in[3];
    const float* lin_b      = (const float*)d_in[4];
    const float* ea_w       = (const float*)d_in[5];
    const float* ea_b       = (const float*)d_in[6];
    const float* attn_w1    = (const float*)d_in[7];
    const float* attn_b1    = (const float*)d_in[8];
    const float* attn_w2    = (const float*)d_in[9];
    const float* attn_b2    = (const float*)d_in[10];

    const int n = in_sizes[0] / IN_C;      // 100000
    const int E = in_sizes[1] / 2;         // 400000

    float* h   = (float*)d_ws;             // [N,16] = 6.4 MB
    float* out = (float*)d_out;

    // out is poisoned 0xAA before every timed launch -> zero it
    hipMemsetAsync(out, 0, (size_t)out_size * sizeof(float), stream);

    h_kernel<<<(n + 15) / 16, 256, 0, stream>>>(x, lin_w, lin_b, h, n);

    edge_kernel<<<(E + 255) / 256, 256, 0, stream>>>(
        edge_index, edge_attr, ea_w, ea_b,
        attn_w1, attn_b1, attn_w2, attn_b2,
        h, out, E);
}

// Round 2
// 142.354 us; speedup vs baseline: 3.1787x; 3.1787x over previous
//
#include <hip/hip_runtime.h>

#define IN_C 64
#define OUT_C 16
#define EA_D 8

// ---------------- h = x @ lin_w + lin_b ----------------
// block = 256 threads = 16 nodes x 16 channels
__global__ __launch_bounds__(256) void h_kernel(
    const float* __restrict__ x,
    const float* __restrict__ lin_w,   // [64,16]
    const float* __restrict__ lin_b,   // [16]
    float* __restrict__ h,             // [N,16]
    int n)
{
    __shared__ float s_w[IN_C * OUT_C];      // 1024
    __shared__ float s_b[OUT_C];
    __shared__ float s_x[16][IN_C + 1];      // +1 pad: kill 4-way bank conflict

    const int t = threadIdx.x;
    for (int i = t; i < IN_C * OUT_C; i += 256) s_w[i] = lin_w[i];
    if (t < OUT_C) s_b[t] = lin_b[t];

    const int nodeBase = blockIdx.x * 16;
    for (int i = t; i < 16 * IN_C; i += 256) {
        const int lr = i / IN_C, k = i % IN_C;
        const int node = nodeBase + lr;
        s_x[lr][k] = (node < n) ? x[node * IN_C + k] : 0.0f;
    }
    __syncthreads();

    const int lr = t >> 4;          // local node 0..15
    const int c  = t & 15;          // channel 0..15
    const int node = nodeBase + lr;
    if (node < n) {
        float acc = s_b[c];
        #pragma unroll
        for (int k = 0; k < IN_C; ++k)
            acc = fmaf(s_x[lr][k], s_w[k * OUT_C + c], acc);
        h[node * OUT_C + c] = acc;
    }
}

// ---------------- per-edge fused kernel ----------------
// Phase A: one thread per edge, all 16 channels in registers.
// Phase B: LDS transpose -> 16 lanes cover one edge's 16 channels so each
//          wave atomic instruction touches 4 cache lines, not 64.
__global__ __launch_bounds__(256) void edge_kernel(
    const int*   __restrict__ edge_index,  // [2,E]
    const float* __restrict__ edge_attr,   // [E,8]
    const float* __restrict__ ea_w,        // [8,16]
    const float* __restrict__ ea_b,        // [16]
    const float* __restrict__ w1,          // [16]
    const float* __restrict__ b1,          // [16]
    const float* __restrict__ w2,          // [16]
    const float* __restrict__ b2,          // [1]
    const float* __restrict__ h,           // [N,16]
    float*       __restrict__ out,         // [N,16]
    int E)
{
    __shared__ float s_eaw[EA_D * OUT_C];  // 128
    __shared__ float s_eab[OUT_C];
    __shared__ float s_w1[OUT_C], s_b1[OUT_C], s_w2[OUT_C];
    __shared__ float s_b2;
    __shared__ float s_val[OUT_C][257];    // SoA by channel, +1 pad
    __shared__ int   s_row[256];

    const int t = threadIdx.x;
    if (t < EA_D * OUT_C)            s_eaw[t]       = ea_w[t];
    else if (t < 128 + OUT_C)        s_eab[t - 128] = ea_b[t - 128];
    else if (t < 144 + OUT_C)        s_w1[t - 144]  = w1[t - 144];
    else if (t < 160 + OUT_C)        s_b1[t - 160]  = b1[t - 160];
    else if (t < 176 + OUT_C)        s_w2[t - 176]  = w2[t - 176];
    else if (t == 192)               s_b2           = b2[0];
    __syncthreads();

    const int e = blockIdx.x * 256 + t;
    const bool valid = (e < E);

    int row = -1;
    float wv[OUT_C];
    #pragma unroll
    for (int c = 0; c < OUT_C; ++c) wv[c] = 0.0f;

    if (valid) {
        row = edge_index[e] - 1;               // edge_index[0][e] - 1
        const int col = edge_index[E + e];     // edge_index[1][e]

        const float4* ap = (const float4*)(edge_attr + (size_t)e * EA_D);
        float4 a0 = ap[0], a1 = ap[1];
        float attr[EA_D] = {a0.x, a0.y, a0.z, a0.w, a1.x, a1.y, a1.z, a1.w};

        const float4* hp = (const float4*)(h + (size_t)col * OUT_C);
        float4 h0 = hp[0], h1 = hp[1], h2 = hp[2], h3 = hp[3];
        float hv[OUT_C] = {h0.x, h0.y, h0.z, h0.w, h1.x, h1.y, h1.z, h1.w,
                           h2.x, h2.y, h2.z, h2.w, h3.x, h3.y, h3.z, h3.w};

        float agg[OUT_C];
        #pragma unroll
        for (int c = 0; c < OUT_C; ++c) {
            float acc = s_eab[c];
            #pragma unroll
            for (int k = 0; k < EA_D; ++k)
                acc = fmaf(attr[k], s_eaw[k * OUT_C + c], acc);
            agg[c] = hv[c] * acc;
        }

        float sc[OUT_C];
        float mx = -1e30f;
        #pragma unroll
        for (int c = 0; c < OUT_C; ++c) {
            float s = s_b2;
            #pragma unroll
            for (int j = 0; j < OUT_C; ++j) {
                float hmid = fmaf(agg[c], s_w1[j], s_b1[j]);
                hmid = fmaxf(hmid, 0.0f);
                s = fmaf(hmid, s_w2[j], s);
            }
            sc[c] = s;
            mx = fmaxf(mx, s);
        }

        float denom = 0.0f;
        #pragma unroll
        for (int c = 0; c < OUT_C; ++c) {
            sc[c] = __expf(sc[c] - mx);
            denom += sc[c];
        }
        const float inv = 1.0f / denom;

        #pragma unroll
        for (int c = 0; c < OUT_C; ++c)
            wv[c] = agg[c] * sc[c] * inv;
    }

    // stash to LDS (SoA: stride-1 writes are conflict-free)
    #pragma unroll
    for (int c = 0; c < OUT_C; ++c) s_val[c][t] = wv[c];
    s_row[t] = row;
    __syncthreads();

    // grouped scatter: 16 consecutive lanes = 16 channels of one edge
    const int c = t & 15;
    #pragma unroll
    for (int it = 0; it < 16; ++it) {
        const int el = it * 16 + (t >> 4);
        const int r  = s_row[el];
        if (r >= 0)
            atomicAdd(out + (size_t)r * OUT_C + c, s_val[c][el]);
    }
}

extern "C" void kernel_launch(void* const* d_in, const int* in_sizes, int n_in,
                              void* d_out, int out_size, void* d_ws, size_t ws_size,
                              hipStream_t stream)
{
    const float* x          = (const float*)d_in[0];
    const int*   edge_index = (const int*)  d_in[1];
    const float* edge_attr  = (const float*)d_in[2];
    const float* lin_w      = (const float*)d_in[3];
    const float* lin_b      = (const float*)d_in[4];
    const float* ea_w       = (const float*)d_in[5];
    const float* ea_b       = (const float*)d_in[6];
    const float* attn_w1    = (const float*)d_in[7];
    const float* attn_b1    = (const float*)d_in[8];
    const float* attn_w2    = (const float*)d_in[9];
    const float* attn_b2    = (const float*)d_in[10];

    const int n = in_sizes[0] / IN_C;      // 100000
    const int E = in_sizes[1] / 2;         // 400000

    float* h   = (float*)d_ws;             // [N,16] = 6.4 MB
    float* out = (float*)d_out;

    hipMemsetAsync(out, 0, (size_t)out_size * sizeof(float), stream);

    h_kernel<<<(n + 15) / 16, 256, 0, stream>>>(x, lin_w, lin_b, h, n);

    edge_kernel<<<(E + 255) / 256, 256, 0, stream>>>(
        edge_index, edge_attr, ea_w, ea_b,
        attn_w1, attn_b1, attn_w2, attn_b2,
        h, out, E);
}

// Round 3
// 136.650 us; speedup vs baseline: 3.3114x; 1.0417x over previous
//
#include <hip/hip_runtime.h>

#define IN_C 64
#define OUT_C 16
#define EA_D 8

__device__ __forceinline__ void atomic_add_f32(float* p, float v) {
#if defined(__HIP_PLATFORM_AMD__) || defined(__AMDGCN__)
    unsafeAtomicAdd(p, v);   // guarantees global_atomic_add_f32 (no CAS loop)
#else
    atomicAdd(p, v);
#endif
}

// ---------------- h = x @ lin_w + lin_b ----------------
// block = 256 threads = 16 nodes x 16 channels
__global__ __launch_bounds__(256) void h_kernel(
    const float* __restrict__ x,
    const float* __restrict__ lin_w,   // [64,16]
    const float* __restrict__ lin_b,   // [16]
    float* __restrict__ h,             // [N,16]
    int n)
{
    __shared__ float s_w[IN_C * OUT_C];      // 1024
    __shared__ float s_b[OUT_C];
    __shared__ float s_x[16][IN_C + 4];      // stride 68: rows 16B-aligned, banks offset by 4

    const int t = threadIdx.x;
    for (int i = t; i < IN_C * OUT_C; i += 256) s_w[i] = lin_w[i];
    if (t < OUT_C) s_b[t] = lin_b[t];

    const int nodeBase = blockIdx.x * 16;
    // cooperative float4 load: 16 rows x 64 floats = 256 float4, one per thread
    {
        const int lr = t >> 4;            // row 0..15
        const int k4 = (t & 15) * 4;      // col 0,4,...,60
        const int node = nodeBase + lr;
        float4 v = make_float4(0.f, 0.f, 0.f, 0.f);
        if (node < n) v = *(const float4*)(x + (size_t)node * IN_C + k4);
        *(float4*)(&s_x[lr][k4]) = v;
    }
    __syncthreads();

    const int lr = t >> 4;          // local node 0..15
    const int c  = t & 15;          // channel 0..15
    const int node = nodeBase + lr;
    if (node < n) {
        float acc = s_b[c];
        #pragma unroll
        for (int k = 0; k < IN_C; ++k)
            acc = fmaf(s_x[lr][k], s_w[k * OUT_C + c], acc);
        h[node * OUT_C + c] = acc;
    }
}

// ---------------- per-edge fused kernel ----------------
// Phase A: one thread per edge, all 16 channels in registers.
// Phase B: LDS transpose -> 16 lanes cover one edge's 16 channels so each
//          wave atomic instruction touches 4 cache lines, not 64.
__global__ __launch_bounds__(256) void edge_kernel(
    const int*   __restrict__ edge_index,  // [2,E]
    const float* __restrict__ edge_attr,   // [E,8]
    const float* __restrict__ ea_w,        // [8,16]
    const float* __restrict__ ea_b,        // [16]
    const float* __restrict__ w1,          // [16]
    const float* __restrict__ b1,          // [16]
    const float* __restrict__ w2,          // [16]
    const float* __restrict__ b2,          // [1]
    const float* __restrict__ h,           // [N,16]
    float*       __restrict__ out,         // [N,16]
    int E)
{
    __shared__ float s_eaw[EA_D * OUT_C];  // 128
    __shared__ float s_eab[OUT_C];
    __shared__ float s_w1[OUT_C], s_b1[OUT_C], s_w2[OUT_C];
    __shared__ float s_b2;
    __shared__ float s_val[OUT_C][257];    // SoA by channel, +1 pad
    __shared__ int   s_row[256];

    const int t = threadIdx.x;
    if (t < EA_D * OUT_C)            s_eaw[t]       = ea_w[t];
    else if (t < 128 + OUT_C)        s_eab[t - 128] = ea_b[t - 128];
    else if (t < 144 + OUT_C)        s_w1[t - 144]  = w1[t - 144];
    else if (t < 160 + OUT_C)        s_b1[t - 160]  = b1[t - 160];
    else if (t < 176 + OUT_C)        s_w2[t - 176]  = w2[t - 176];
    else if (t == 192)               s_b2           = b2[0];
    __syncthreads();

    const int e = blockIdx.x * 256 + t;
    const bool valid = (e < E);

    int row = -1;
    float wv[OUT_C];
    #pragma unroll
    for (int c = 0; c < OUT_C; ++c) wv[c] = 0.0f;

    if (valid) {
        row = edge_index[e] - 1;               // edge_index[0][e] - 1
        const int col = edge_index[E + e];     // edge_index[1][e]

        const float4* ap = (const float4*)(edge_attr + (size_t)e * EA_D);
        float4 a0 = ap[0], a1 = ap[1];
        float attr[EA_D] = {a0.x, a0.y, a0.z, a0.w, a1.x, a1.y, a1.z, a1.w};

        const float4* hp = (const float4*)(h + (size_t)col * OUT_C);
        float4 h0 = hp[0], h1 = hp[1], h2 = hp[2], h3 = hp[3];
        float hv[OUT_C] = {h0.x, h0.y, h0.z, h0.w, h1.x, h1.y, h1.z, h1.w,
                           h2.x, h2.y, h2.z, h2.w, h3.x, h3.y, h3.z, h3.w};

        float agg[OUT_C];
        #pragma unroll
        for (int c = 0; c < OUT_C; ++c) {
            float acc = s_eab[c];
            #pragma unroll
            for (int k = 0; k < EA_D; ++k)
                acc = fmaf(attr[k], s_eaw[k * OUT_C + c], acc);
            agg[c] = hv[c] * acc;
        }

        float sc[OUT_C];
        float mx = -1e30f;
        #pragma unroll
        for (int c = 0; c < OUT_C; ++c) {
            float s = s_b2;
            #pragma unroll
            for (int j = 0; j < OUT_C; ++j) {
                float hmid = fmaf(agg[c], s_w1[j], s_b1[j]);
                hmid = fmaxf(hmid, 0.0f);
                s = fmaf(hmid, s_w2[j], s);
            }
            sc[c] = s;
            mx = fmaxf(mx, s);
        }

        float denom = 0.0f;
        #pragma unroll
        for (int c = 0; c < OUT_C; ++c) {
            sc[c] = __expf(sc[c] - mx);
            denom += sc[c];
        }
        const float inv = 1.0f / denom;

        #pragma unroll
        for (int c = 0; c < OUT_C; ++c)
            wv[c] = agg[c] * sc[c] * inv;
    }

    // stash to LDS (SoA: stride-1 writes are conflict-free)
    #pragma unroll
    for (int c = 0; c < OUT_C; ++c) s_val[c][t] = wv[c];
    s_row[t] = row;
    __syncthreads();

    // grouped scatter: 16 consecutive lanes = 16 channels of one edge
    const int c = t & 15;
    #pragma unroll
    for (int it = 0; it < 16; ++it) {
        const int el = it * 16 + (t >> 4);
        const int r  = s_row[el];
        if (r >= 0)
            atomic_add_f32(out + (size_t)r * OUT_C + c, s_val[c][el]);
    }
}

extern "C" void kernel_launch(void* const* d_in, const int* in_sizes, int n_in,
                              void* d_out, int out_size, void* d_ws, size_t ws_size,
                              hipStream_t stream)
{
    const float* x          = (const float*)d_in[0];
    const int*   edge_index = (const int*)  d_in[1];
    const float* edge_attr  = (const float*)d_in[2];
    const float* lin_w      = (const float*)d_in[3];
    const float* lin_b      = (const float*)d_in[4];
    const float* ea_w       = (const float*)d_in[5];
    const float* ea_b       = (const float*)d_in[6];
    const float* attn_w1    = (const float*)d_in[7];
    const float* attn_b1    = (const float*)d_in[8];
    const float* attn_w2    = (const float*)d_in[9];
    const float* attn_b2    = (const float*)d_in[10];

    const int n = in_sizes[0] / IN_C;      // 100000
    const int E = in_sizes[1] / 2;         // 400000

    float* h   = (float*)d_ws;             // [N,16] = 6.4 MB
    float* out = (float*)d_out;

    hipMemsetAsync(out, 0, (size_t)out_size * sizeof(float), stream);

    h_kernel<<<(n + 15) / 16, 256, 0, stream>>>(x, lin_w, lin_b, h, n);

    edge_kernel<<<(E + 255) / 256, 256, 0, stream>>>(
        edge_index, edge_attr, ea_w, ea_b,
        attn_w1, attn_b1, attn_w2, attn_b2,
        h, out, E);
}